// Round 1
// baseline (121.620 us; speedup 1.0000x reference)
//
#include <hip/hip_runtime.h>
#include <hip/hip_bf16.h>
#include <math.h>

#define N_ROWS 4096
#define D 512
#define TWO_N 8192
#define TILE 128
#define BK 64
#define NJB (TWO_N / TILE)   /* 64 column blocks */
#define INV_T 5.0f           /* 1/temperature */

typedef __attribute__((ext_vector_type(8))) __bf16 bf16x8;
typedef __attribute__((ext_vector_type(4))) float f32x4;

// ---------------- block reduction helper (broadcasts result) ----------------
template<int K>
__device__ inline void block_reduce_bcast(float (&v)[K]) {
  __shared__ float red[4][K];
  const int t = threadIdx.x;
  #pragma unroll
  for (int off = 32; off; off >>= 1)
    #pragma unroll
    for (int i = 0; i < K; ++i) v[i] += __shfl_xor(v[i], off, 64);
  __syncthreads();
  if ((t & 63) == 0)
    #pragma unroll
    for (int i = 0; i < K; ++i) red[t >> 6][i] = v[i];
  __syncthreads();
  #pragma unroll
  for (int i = 0; i < K; ++i) v[i] = red[0][i] + red[1][i] + red[2][i] + red[3][i];
}

// ---------------- kernel 1: normalize rows, emit bf16 reps + fp32 stats ----
__global__ __launch_bounds__(256) void normalize_kernel(
    const float* __restrict__ ei_, const float* __restrict__ ej_,
    const float* __restrict__ ek_,
    __hip_bfloat16* __restrict__ reps, float* __restrict__ diagexp,
    float* __restrict__ pos_ij, float* __restrict__ exp_ik)
{
  const int n = blockIdx.x;
  const int t = threadIdx.x;
  const long base = (long)n * D + 2 * t;
  const float2 ei = *reinterpret_cast<const float2*>(ei_ + base);
  const float2 ej = *reinterpret_cast<const float2*>(ej_ + base);
  const float2 ek = *reinterpret_cast<const float2*>(ek_ + base);

  float v[5];
  v[0] = ei.x * ei.x + ei.y * ei.y;   // ||e_i||^2
  v[1] = ej.x * ej.x + ej.y * ej.y;   // ||e_j||^2
  v[2] = ek.x * ek.x + ek.y * ek.y;   // ||e_k||^2
  v[3] = ei.x * ej.x + ei.y * ej.y;   // <e_i, e_j>
  v[4] = ek.x * ei.x + ek.y * ei.y;   // <e_k, e_i>
  block_reduce_bcast<5>(v);

  const float ni = fmaxf(sqrtf(v[0]), 1e-12f);
  const float nj = fmaxf(sqrtf(v[1]), 1e-12f);
  const float nk = fmaxf(sqrtf(v[2]), 1e-12f);
  const float invi = 1.0f / ni, invj = 1.0f / nj;

  __hip_bfloat162 pi, pj;
  pi.x = __float2bfloat16(ei.x * invi);
  pi.y = __float2bfloat16(ei.y * invi);
  pj.x = __float2bfloat16(ej.x * invj);
  pj.y = __float2bfloat16(ej.y * invj);
  *reinterpret_cast<__hip_bfloat162*>(reps + (long)n * D + 2 * t) = pi;
  *reinterpret_cast<__hip_bfloat162*>(reps + (long)(N_ROWS + n) * D + 2 * t) = pj;

  float q[2];
  {
    float f0 = __bfloat162float(pi.x), f1 = __bfloat162float(pi.y);
    q[0] = f0 * f0 + f1 * f1;
    f0 = __bfloat162float(pj.x); f1 = __bfloat162float(pj.y);
    q[1] = f0 * f0 + f1 * f1;
  }
  block_reduce_bcast<2>(q);

  if (t == 0) {
    diagexp[n]          = __expf(INV_T * q[0]);   // exp(5*||q(z_i)||^2)
    diagexp[N_ROWS + n] = __expf(INV_T * q[1]);   // exp(5*||q(z_j)||^2)
    pos_ij[n] = v[3] / (ni * nj);                 // exact fp32 positive
    exp_ik[n] = __expf(INV_T * v[4] / (nk * ni)); // exp(5*sim_ik)
  }
}

// ---------------- kernel 2: reduce the two scalars --------------------------
__global__ __launch_bounds__(256) void scalar_kernel(
    const float* __restrict__ pos_ij, const float* __restrict__ exp_ik,
    float* __restrict__ scalars)
{
  const int t = threadIdx.x;
  float v[2] = {0.f, 0.f};
  for (int i = t; i < N_ROWS; i += 256) { v[0] += pos_ij[i]; v[1] += exp_ik[i]; }
  block_reduce_bcast<2>(v);
  if (t == 0) { scalars[0] = v[0]; scalars[1] = v[1]; }
}

// ---------------- kernel 3: fused Z*Z^T GEMM + exp + row-sum ---------------
__global__ __launch_bounds__(256) void gemm_expsum_kernel(
    const __hip_bfloat16* __restrict__ reps, float* __restrict__ S_partial)
{
  __shared__ __align__(16) __hip_bfloat16 As[TILE][BK];   // 16 KB
  __shared__ __align__(16) __hip_bfloat16 Bs[TILE][BK];   // 16 KB
  __shared__ float rowbuf[2][TILE];                       // 1 KB

  const int J = blockIdx.x;      // column block (reps rows as B^T)
  const int I = blockIdx.y;      // row block
  const int t = threadIdx.x;
  const int l = t & 63;
  const int w = t >> 6;          // wave 0..3
  const int wr = w >> 1;         // wave row 0..1
  const int wc = w & 1;          // wave col 0..1
  const long rI = (long)I * TILE;
  const long cJ = (long)J * TILE;

  f32x4 acc[4][4];
  #pragma unroll
  for (int a = 0; a < 4; ++a)
    #pragma unroll
    for (int b = 0; b < 4; ++b) { f32x4 z = {0.f, 0.f, 0.f, 0.f}; acc[a][b] = z; }

  for (int kt = 0; kt < D; kt += BK) {
    if (kt) __syncthreads();   // previous tile's reads done before overwrite
    // stage A (rows rI..rI+127) and B (rows cJ..cJ+127), K slice [kt, kt+64)
    #pragma unroll
    for (int c = 0; c < 4; ++c) {
      const int idx = c * 256 + t;
      const int row = idx >> 3;            // 0..127
      const int col = (idx & 7) * 8;       // 0..56, 8 bf16 = 16 B per lane
      const __hip_bfloat16* gA = reps + (rI + row) * D + kt + col;
      const __hip_bfloat16* gB = reps + (cJ + row) * D + kt + col;
      __hip_bfloat16* lA = &As[0][0] + (long)(c * 256 + w * 64) * 8;
      __hip_bfloat16* lB = &Bs[0][0] + (long)(c * 256 + w * 64) * 8;
      __builtin_amdgcn_global_load_lds(
          (const __attribute__((address_space(1))) void*)gA,
          (__attribute__((address_space(3))) void*)lA, 16, 0, 0);
      __builtin_amdgcn_global_load_lds(
          (const __attribute__((address_space(1))) void*)gB,
          (__attribute__((address_space(3))) void*)lB, 16, 0, 0);
    }
    __syncthreads();           // compiler drains vmcnt before barrier

    #pragma unroll
    for (int kk = 0; kk < 2; ++kk) {
      bf16x8 av[4], bv[4];
      #pragma unroll
      for (int mi = 0; mi < 4; ++mi)
        av[mi] = *reinterpret_cast<const bf16x8*>(
            &As[wr * 64 + mi * 16 + (l & 15)][kk * 32 + (l >> 4) * 8]);
      #pragma unroll
      for (int ni = 0; ni < 4; ++ni)
        bv[ni] = *reinterpret_cast<const bf16x8*>(
            &Bs[wc * 64 + ni * 16 + (l & 15)][kk * 32 + (l >> 4) * 8]);
      #pragma unroll
      for (int mi = 0; mi < 4; ++mi)
        #pragma unroll
        for (int ni = 0; ni < 4; ++ni)
          acc[mi][ni] = __builtin_amdgcn_mfma_f32_16x16x32_bf16(
              av[mi], bv[ni], acc[mi][ni], 0, 0, 0);
    }
  }

  // epilogue: exp(5*sim) and per-row sums over this 128-col block
  // frag element j: row = (l>>4)*4 + j, col = l&15  (m89-verified)
  #pragma unroll
  for (int mi = 0; mi < 4; ++mi) {
    float vsum[4];
    #pragma unroll
    for (int j = 0; j < 4; ++j) {
      float s = 0.f;
      #pragma unroll
      for (int ni = 0; ni < 4; ++ni) s += __expf(INV_T * acc[mi][ni][j]);
      vsum[j] = s;
    }
    #pragma unroll
    for (int off = 1; off < 16; off <<= 1)
      #pragma unroll
      for (int j = 0; j < 4; ++j) vsum[j] += __shfl_xor(vsum[j], off, 64);
    if ((l & 15) == 0) {
      const int rloc = wr * 64 + mi * 16 + (l >> 4) * 4;
      #pragma unroll
      for (int j = 0; j < 4; ++j) rowbuf[wc][rloc + j] = vsum[j];
    }
  }
  __syncthreads();
  if (t < TILE)
    S_partial[(long)J * TWO_N + rI + t] = rowbuf[0][t] + rowbuf[1][t];
}

// ---------------- kernel 4: per-row log(denominator), block partials -------
__global__ __launch_bounds__(256) void rowlog_kernel(
    const float* __restrict__ S_partial, const float* __restrict__ diagexp,
    const float* __restrict__ scalars, float* __restrict__ blockpart)
{
  const int t = threadIdx.x;
  const int r = blockIdx.x * 256 + t;
  float s = 0.f;
  #pragma unroll 8
  for (int Jb = 0; Jb < NJB; ++Jb) s += S_partial[(long)Jb * TWO_N + r];
  const float denom_fu = 2.0f * scalars[1];
  float v[1];
  v[0] = logf(s - diagexp[r] + denom_fu);
  block_reduce_bcast<1>(v);
  if (t == 0) blockpart[blockIdx.x] = v[0];
}

// ---------------- kernel 5: final scalar -----------------------------------
__global__ void final_kernel(const float* __restrict__ blockpart,
                             const float* __restrict__ scalars,
                             float* __restrict__ out)
{
  const int t = threadIdx.x;   // 64 threads
  float s = (t < TWO_N / 256) ? blockpart[t] : 0.f;
  #pragma unroll
  for (int off = 32; off; off >>= 1) s += __shfl_xor(s, off, 64);
  if (t == 0) out[0] = (s - 10.0f * scalars[0]) / (float)TWO_N;
}

extern "C" void kernel_launch(void* const* d_in, const int* in_sizes, int n_in,
                              void* d_out, int out_size, void* d_ws, size_t ws_size,
                              hipStream_t stream)
{
  const float* ei = (const float*)d_in[0];
  const float* ej = (const float*)d_in[1];
  const float* ek = (const float*)d_in[2];
  float* out = (float*)d_out;

  char* ws = (char*)d_ws;
  __hip_bfloat16* reps = (__hip_bfloat16*)ws;                          // 8 MB
  float* S_partial = (float*)(ws + 8u * 1024 * 1024);                  // 2 MB
  float* diagexp   = (float*)(ws + 10u * 1024 * 1024);                 // 32 KB
  float* pos_ij    = (float*)(ws + 10u * 1024 * 1024 + 32 * 1024);     // 16 KB
  float* exp_ik    = (float*)(ws + 10u * 1024 * 1024 + 48 * 1024);     // 16 KB
  float* scalars   = (float*)(ws + 10u * 1024 * 1024 + 64 * 1024);     // 8 B
  float* blockpart = (float*)(ws + 10u * 1024 * 1024 + 64 * 1024 + 256); // 128 B

  normalize_kernel<<<N_ROWS, 256, 0, stream>>>(ei, ej, ek, reps, diagexp,
                                               pos_ij, exp_ik);
  scalar_kernel<<<1, 256, 0, stream>>>(pos_ij, exp_ik, scalars);
  dim3 grid(NJB, TWO_N / TILE);
  gemm_expsum_kernel<<<grid, 256, 0, stream>>>(reps, S_partial);
  rowlog_kernel<<<TWO_N / 256, 256, 0, stream>>>(S_partial, diagexp, scalars,
                                                 blockpart);
  final_kernel<<<1, 64, 0, stream>>>(blockpart, scalars, out);
}

// Round 2
// 81.877 us; speedup vs baseline: 1.4854x; 1.4854x over previous
//
#include <hip/hip_runtime.h>
#include <hip/hip_bf16.h>
#include <math.h>

#define N_ROWS 4096
#define D 512
#define TWO_N 8192
#define TILE 128
#define BK 64
#define NJB (TWO_N / TILE)   /* 64 column blocks */
#define NPAIRS (NJB * (NJB + 1) / 2)   /* 2080 upper-tri blocks */
#define INV_T 5.0f           /* 1/temperature */

typedef __attribute__((ext_vector_type(8))) __bf16 bf16x8;
typedef __attribute__((ext_vector_type(4))) float f32x4;

// ---------------- block reduction helper (broadcasts result) ----------------
template<int K>
__device__ inline void block_reduce_bcast(float (&v)[K]) {
  __shared__ float red[4][K];
  const int t = threadIdx.x;
  #pragma unroll
  for (int off = 32; off; off >>= 1)
    #pragma unroll
    for (int i = 0; i < K; ++i) v[i] += __shfl_xor(v[i], off, 64);
  __syncthreads();
  if ((t & 63) == 0)
    #pragma unroll
    for (int i = 0; i < K; ++i) red[t >> 6][i] = v[i];
  __syncthreads();
  #pragma unroll
  for (int i = 0; i < K; ++i) v[i] = red[0][i] + red[1][i] + red[2][i] + red[3][i];
}

// ---------------- kernel 1: normalize rows, emit bf16 reps + fp32 stats ----
__global__ __launch_bounds__(256) void normalize_kernel(
    const float* __restrict__ ei_, const float* __restrict__ ej_,
    const float* __restrict__ ek_,
    __hip_bfloat16* __restrict__ reps, float* __restrict__ diagexp,
    float* __restrict__ pos_ij, float* __restrict__ exp_ik)
{
  const int n = blockIdx.x;
  const int t = threadIdx.x;
  const long base = (long)n * D + 2 * t;
  const float2 ei = *reinterpret_cast<const float2*>(ei_ + base);
  const float2 ej = *reinterpret_cast<const float2*>(ej_ + base);
  const float2 ek = *reinterpret_cast<const float2*>(ek_ + base);

  float v[5];
  v[0] = ei.x * ei.x + ei.y * ei.y;   // ||e_i||^2
  v[1] = ej.x * ej.x + ej.y * ej.y;   // ||e_j||^2
  v[2] = ek.x * ek.x + ek.y * ek.y;   // ||e_k||^2
  v[3] = ei.x * ej.x + ei.y * ej.y;   // <e_i, e_j>
  v[4] = ek.x * ei.x + ek.y * ei.y;   // <e_k, e_i>
  block_reduce_bcast<5>(v);

  const float ni = fmaxf(sqrtf(v[0]), 1e-12f);
  const float nj = fmaxf(sqrtf(v[1]), 1e-12f);
  const float nk = fmaxf(sqrtf(v[2]), 1e-12f);
  const float invi = 1.0f / ni, invj = 1.0f / nj;

  __hip_bfloat162 pi, pj;
  pi.x = __float2bfloat16(ei.x * invi);
  pi.y = __float2bfloat16(ei.y * invi);
  pj.x = __float2bfloat16(ej.x * invj);
  pj.y = __float2bfloat16(ej.y * invj);
  *reinterpret_cast<__hip_bfloat162*>(reps + (long)n * D + 2 * t) = pi;
  *reinterpret_cast<__hip_bfloat162*>(reps + (long)(N_ROWS + n) * D + 2 * t) = pj;

  float q[2];
  {
    float f0 = __bfloat162float(pi.x), f1 = __bfloat162float(pi.y);
    q[0] = f0 * f0 + f1 * f1;
    f0 = __bfloat162float(pj.x); f1 = __bfloat162float(pj.y);
    q[1] = f0 * f0 + f1 * f1;
  }
  block_reduce_bcast<2>(q);

  if (t == 0) {
    diagexp[n]          = __expf(INV_T * q[0]);   // exp(5*||q(z_i)||^2)
    diagexp[N_ROWS + n] = __expf(INV_T * q[1]);   // exp(5*||q(z_j)||^2)
    pos_ij[n] = v[3] / (ni * nj);                 // exact fp32 positive
    exp_ik[n] = __expf(INV_T * v[4] / (nk * ni)); // exp(5*sim_ik)
  }
}

// ---------------- kernel 2: reduce the two scalars --------------------------
__global__ __launch_bounds__(256) void scalar_kernel(
    const float* __restrict__ pos_ij, const float* __restrict__ exp_ik,
    float* __restrict__ scalars)
{
  const int t = threadIdx.x;
  float v[2] = {0.f, 0.f};
  for (int i = t; i < N_ROWS; i += 256) { v[0] += pos_ij[i]; v[1] += exp_ik[i]; }
  block_reduce_bcast<2>(v);
  if (t == 0) { scalars[0] = v[0]; scalars[1] = v[1]; }
}

// ---------------- kernel 3: fused Z*Z^T GEMM + exp + row/col sums ----------
// Symmetry: exp(5*sim) is symmetric, so block (I,J), I<=J contributes
//   row-sums  -> S_partial[J][rows of I]
//   col-sums  -> S_partial[I][rows of J]   (skip when I==J)
// Each (slot,row) has exactly one writer: block {min(slot,rowblk),max(...)}.
__global__ __launch_bounds__(256) void gemm_expsum_kernel(
    const __hip_bfloat16* __restrict__ reps, float* __restrict__ S_partial)
{
  __shared__ __align__(16) __hip_bfloat16 As[TILE][BK];   // 16 KB
  __shared__ __align__(16) __hip_bfloat16 Bs[TILE][BK];   // 16 KB
  __shared__ float rowbuf[2][TILE];                       // indexed by wc
  __shared__ float colbuf[2][TILE];                       // indexed by wr

  // decode upper-triangular pair (I <= J) from 1-D block index
  int k = blockIdx.x;
  int I = 0;
  while (k >= NJB - I) { k -= NJB - I; ++I; }
  const int J = I + k;

  const int t = threadIdx.x;
  const int l = t & 63;
  const int w = t >> 6;          // wave 0..3
  const int wr = w >> 1;         // wave row 0..1
  const int wc = w & 1;          // wave col 0..1
  const long rI = (long)I * TILE;
  const long cJ = (long)J * TILE;

  f32x4 acc[4][4];
  #pragma unroll
  for (int a = 0; a < 4; ++a)
    #pragma unroll
    for (int b = 0; b < 4; ++b) { f32x4 z = {0.f, 0.f, 0.f, 0.f}; acc[a][b] = z; }

  for (int kt = 0; kt < D; kt += BK) {
    if (kt) __syncthreads();   // previous tile's reads done before overwrite
    #pragma unroll
    for (int c = 0; c < 4; ++c) {
      const int idx = c * 256 + t;
      const int row = idx >> 3;            // 0..127
      const int col = (idx & 7) * 8;       // 8 bf16 = 16 B per lane
      const __hip_bfloat16* gA = reps + (rI + row) * D + kt + col;
      const __hip_bfloat16* gB = reps + (cJ + row) * D + kt + col;
      __hip_bfloat16* lA = &As[0][0] + (long)(c * 256 + w * 64) * 8;
      __hip_bfloat16* lB = &Bs[0][0] + (long)(c * 256 + w * 64) * 8;
      __builtin_amdgcn_global_load_lds(
          (const __attribute__((address_space(1))) void*)gA,
          (__attribute__((address_space(3))) void*)lA, 16, 0, 0);
      __builtin_amdgcn_global_load_lds(
          (const __attribute__((address_space(1))) void*)gB,
          (__attribute__((address_space(3))) void*)lB, 16, 0, 0);
    }
    __syncthreads();           // compiler drains vmcnt before barrier

    #pragma unroll
    for (int kk = 0; kk < 2; ++kk) {
      bf16x8 av[4], bv[4];
      #pragma unroll
      for (int mi = 0; mi < 4; ++mi)
        av[mi] = *reinterpret_cast<const bf16x8*>(
            &As[wr * 64 + mi * 16 + (l & 15)][kk * 32 + (l >> 4) * 8]);
      #pragma unroll
      for (int ni = 0; ni < 4; ++ni)
        bv[ni] = *reinterpret_cast<const bf16x8*>(
            &Bs[wc * 64 + ni * 16 + (l & 15)][kk * 32 + (l >> 4) * 8]);
      #pragma unroll
      for (int mi = 0; mi < 4; ++mi)
        #pragma unroll
        for (int ni = 0; ni < 4; ++ni)
          acc[mi][ni] = __builtin_amdgcn_mfma_f32_16x16x32_bf16(
              av[mi], bv[ni], acc[mi][ni], 0, 0, 0);
    }
  }

  // epilogue: e = exp(5*sim); row-sums (this tile's rows) and col-sums
  // frag element j: row = (l>>4)*4 + j, col = l&15  (m89-verified)
  float rsum[4][4];   // [mi][j]
  float csum[4];      // [ni]
  #pragma unroll
  for (int mi = 0; mi < 4; ++mi)
    #pragma unroll
    for (int j = 0; j < 4; ++j) rsum[mi][j] = 0.f;
  #pragma unroll
  for (int ni = 0; ni < 4; ++ni) csum[ni] = 0.f;

  #pragma unroll
  for (int mi = 0; mi < 4; ++mi)
    #pragma unroll
    for (int ni = 0; ni < 4; ++ni)
      #pragma unroll
      for (int j = 0; j < 4; ++j) {
        const float e = __expf(INV_T * acc[mi][ni][j]);
        rsum[mi][j] += e;
        csum[ni]    += e;
      }

  // row reduce: sum across cols (lane bits 0-3)
  #pragma unroll
  for (int mi = 0; mi < 4; ++mi) {
    #pragma unroll
    for (int off = 1; off < 16; off <<= 1)
      #pragma unroll
      for (int j = 0; j < 4; ++j) rsum[mi][j] += __shfl_xor(rsum[mi][j], off, 64);
    if ((l & 15) == 0) {
      const int rloc = wr * 64 + mi * 16 + (l >> 4) * 4;
      #pragma unroll
      for (int j = 0; j < 4; ++j) rowbuf[wc][rloc + j] = rsum[mi][j];
    }
  }
  // col reduce: sum across row-groups (lane bits 4-5)
  #pragma unroll
  for (int off = 16; off < 64; off <<= 1)
    #pragma unroll
    for (int ni = 0; ni < 4; ++ni) csum[ni] += __shfl_xor(csum[ni], off, 64);
  if (l < 16) {
    #pragma unroll
    for (int ni = 0; ni < 4; ++ni)
      colbuf[wr][wc * 64 + ni * 16 + l] = csum[ni];
  }
  __syncthreads();

  if (t < TILE) {
    S_partial[(long)J * TWO_N + rI + t] = rowbuf[0][t] + rowbuf[1][t];
  } else if (I != J) {
    const int c = t - TILE;
    S_partial[(long)I * TWO_N + cJ + c] = colbuf[0][c] + colbuf[1][c];
  }
}

// ---------------- kernel 4: per-row log(denominator), block partials -------
__global__ __launch_bounds__(256) void rowlog_kernel(
    const float* __restrict__ S_partial, const float* __restrict__ diagexp,
    const float* __restrict__ scalars, float* __restrict__ blockpart)
{
  const int t = threadIdx.x;
  const int r = blockIdx.x * 256 + t;
  float s = 0.f;
  #pragma unroll 8
  for (int Jb = 0; Jb < NJB; ++Jb) s += S_partial[(long)Jb * TWO_N + r];
  const float denom_fu = 2.0f * scalars[1];
  float v[1];
  v[0] = logf(s - diagexp[r] + denom_fu);
  block_reduce_bcast<1>(v);
  if (t == 0) blockpart[blockIdx.x] = v[0];
}

// ---------------- kernel 5: final scalar -----------------------------------
__global__ void final_kernel(const float* __restrict__ blockpart,
                             const float* __restrict__ scalars,
                             float* __restrict__ out)
{
  const int t = threadIdx.x;   // 64 threads
  float s = (t < TWO_N / 256) ? blockpart[t] : 0.f;
  #pragma unroll
  for (int off = 32; off; off >>= 1) s += __shfl_xor(s, off, 64);
  if (t == 0) out[0] = (s - 10.0f * scalars[0]) / (float)TWO_N;
}

extern "C" void kernel_launch(void* const* d_in, const int* in_sizes, int n_in,
                              void* d_out, int out_size, void* d_ws, size_t ws_size,
                              hipStream_t stream)
{
  const float* ei = (const float*)d_in[0];
  const float* ej = (const float*)d_in[1];
  const float* ek = (const float*)d_in[2];
  float* out = (float*)d_out;

  char* ws = (char*)d_ws;
  __hip_bfloat16* reps = (__hip_bfloat16*)ws;                          // 8 MB
  float* S_partial = (float*)(ws + 8u * 1024 * 1024);                  // 2 MB
  float* diagexp   = (float*)(ws + 10u * 1024 * 1024);                 // 32 KB
  float* pos_ij    = (float*)(ws + 10u * 1024 * 1024 + 32 * 1024);     // 16 KB
  float* exp_ik    = (float*)(ws + 10u * 1024 * 1024 + 48 * 1024);     // 16 KB
  float* scalars   = (float*)(ws + 10u * 1024 * 1024 + 64 * 1024);     // 8 B
  float* blockpart = (float*)(ws + 10u * 1024 * 1024 + 64 * 1024 + 256); // 128 B

  normalize_kernel<<<N_ROWS, 256, 0, stream>>>(ei, ej, ek, reps, diagexp,
                                               pos_ij, exp_ik);
  scalar_kernel<<<1, 256, 0, stream>>>(pos_ij, exp_ik, scalars);
  gemm_expsum_kernel<<<NPAIRS, 256, 0, stream>>>(reps, S_partial);
  rowlog_kernel<<<TWO_N / 256, 256, 0, stream>>>(S_partial, diagexp, scalars,
                                                 blockpart);
  final_kernel<<<1, 64, 0, stream>>>(blockpart, scalars, out);
}